// Round 4
// baseline (301.833 us; speedup 1.0000x reference)
//
#include <hip/hip_runtime.h>
#include <cmath>

#define NUM_POS 10
#define NEG 1000
#define COLS 1010          // NUM_POS + NEG
#define BATCH 4096
#define USERS 10001
#define ITEMS 10001
#define R_TOT (BATCH * NUM_POS)   // 40960
#define HSIZE (1 << 16)
#define GAMMA0 0.1f
#define EPSV 1e-10f

#define N_U 100020001LL            // USERS*ITEMS elements in u
// out[0]=loss, out[1..N_U]=u_new.  Quads on out's 16B grid: out4[k]=out[4k..4k+3]
// valid full quads: k = 1 .. 25004999  (covers out[4..100019999])
#define KMAX 25005000LL

// ---- copy kernel: out4[k] = load16(u + 4k - 1)  (misaligned load, aligned store) ----
__global__ void k_copy(const float* __restrict__ u, float* __restrict__ out) {
    float4* __restrict__ o4 = (float4*)out;
    long long stride = (long long)gridDim.x * blockDim.x;
    long long k = 1 + (long long)blockIdx.x * blockDim.x + threadIdx.x;
    for (; k + stride < KMAX; k += 2 * stride) {
        long long k1 = k + stride;
        float4 t0, t1;
        __builtin_memcpy(&t0, u + 4 * k  - 1, sizeof(float4));   // align-4 dwordx4
        __builtin_memcpy(&t1, u + 4 * k1 - 1, sizeof(float4));
        o4[k]  = t0;                                             // aligned 16B store
        o4[k1] = t1;
    }
    if (k < KMAX) {
        float4 t;
        __builtin_memcpy(&t, u + 4 * k - 1, sizeof(float4));
        o4[k] = t;
    }
    if (blockIdx.x == 0 && threadIdx.x == 0) {
        out[1] = u[0]; out[2] = u[1]; out[3] = u[2];
        out[100020000] = u[100019999];
        out[100020001] = u[100020000];
    }
}

// ---- kernel 1: per-row max(neg)-min(pos), fused global max via encoded atomicMin ----
__device__ __forceinline__ unsigned enc_float(float f) {
    unsigned ub = __float_as_uint(f);
    return (ub & 0x80000000u) ? ~ub : (ub | 0x80000000u);
}
__device__ __forceinline__ float dec_inv(unsigned inv) {
    unsigned enc = ~inv;
    unsigned ub = (enc & 0x80000000u) ? (enc & 0x7FFFFFFFu) : ~enc;
    return __uint_as_float(ub);
}

__global__ void k_rowstat(const float* __restrict__ pred, unsigned* __restrict__ Minv) {
    int b = blockIdx.x;
    const float2* row2 = (const float2*)(pred + (size_t)b * COLS);  // 8B-aligned
    float mn = INFINITY, mx = -INFINITY;
    for (int i = threadIdx.x; i < 505; i += 256) {
        float2 v = row2[i];
        if (i < 5) mn = fminf(mn, fminf(v.x, v.y));   // elements 0..9  (pos)
        else       mx = fmaxf(mx, fmaxf(v.x, v.y));   // elements 10..1009 (neg)
    }
    __shared__ float smn[4], smx[4];
    int lane = threadIdx.x & 63, wid = threadIdx.x >> 6;
    for (int off = 32; off; off >>= 1) {
        mn = fminf(mn, __shfl_down(mn, off));
        mx = fmaxf(mx, __shfl_down(mx, off));
    }
    if (lane == 0) { smn[wid] = mn; smx[wid] = mx; }
    __syncthreads();
    if (threadIdx.x == 0) {
        mn = fminf(fminf(smn[0], smn[1]), fminf(smn[2], smn[3]));
        mx = fmaxf(fmaxf(smx[0], smx[1]), fmaxf(smx[2], smx[3]));
        atomicMin(Minv, ~enc_float(mx - mn));   // global max via min of inverted code
    }
}

// -------- kernel 2: per-row E,F sums; emit meanexp/sumS/keys; fused hash insert --------
__device__ __forceinline__ unsigned hash_key(int k) {
    return (((unsigned)k * 2654435761u) >> 13) & (HSIZE - 1);
}

__global__ void k_rowsums(const float* __restrict__ pred, const unsigned* __restrict__ Minv,
                          const int* __restrict__ user_id, const int* __restrict__ item_id,
                          float* __restrict__ meanexp, float* __restrict__ sumS,
                          int* __restrict__ keys, int* __restrict__ hkey,
                          int* __restrict__ hval) {
    int b = blockIdx.x;
    float M = dec_inv(Minv[0]);
    const float* row = pred + (size_t)b * COLS;
    const float2* row2 = (const float2*)row;
    float e = 0.f, f = 0.f;
    for (int i = 5 + threadIdx.x; i < 505; i += 256) {   // elements 10..1009 (neg)
        float2 v = row2[i];
        float w0 = expf(v.x - M), w1 = expf(v.y - M);
        e += w0 + w1;
        f += v.x * w0 + v.y * w1;
    }
    __shared__ float sh[8], bc[2];
    int lane = threadIdx.x & 63, wid = threadIdx.x >> 6;
    for (int off = 32; off; off >>= 1) { e += __shfl_down(e, off); f += __shfl_down(f, off); }
    if (lane == 0) { sh[wid] = e; sh[4 + wid] = f; }
    __syncthreads();
    if (threadIdx.x == 0) {
        bc[0] = (sh[0] + sh[1]) + (sh[2] + sh[3]);
        bc[1] = (sh[4] + sh[5]) + (sh[6] + sh[7]);
    }
    __syncthreads();
    if (threadIdx.x < NUM_POS) {
        float E = bc[0], F = bc[1];
        int p = threadIdx.x;
        int r = b * NUM_POS + p;
        float pos = row[p];
        float s = expf(-pos);
        meanexp[r] = s * E * (1.0f / NEG);
        sumS[r]    = s * (F - pos * E);
        int key = user_id[b] * ITEMS + item_id[r];
        keys[r] = key;
        // hash insert: winner = max r per key (last write wins)
        unsigned sl = hash_key(key);
        while (true) {
            int old = atomicCAS(&hkey[sl], -1, key);
            if (old == -1 || old == key) { atomicMax(&hval[sl], r); break; }
            sl = (sl + 1) & (HSIZE - 1);
        }
    }
}

// -------- kernel 3: scatter winners into u_out, accumulate loss partials --------
__global__ void k_scatter_loss(const float* __restrict__ u_in,
                               const float* __restrict__ meanexp,
                               const float* __restrict__ sumS,
                               const int* __restrict__ keys,
                               const int* __restrict__ hkey, const int* __restrict__ hval,
                               float* __restrict__ u_out, float* __restrict__ partial) {
    int r = blockIdx.x * 256 + threadIdx.x;
    int k = keys[r];
    unsigned s = hash_key(k);
    while (hkey[s] != k) s = (s + 1) & (HSIZE - 1);
    int win = hval[s];                       // last duplicate index wins
    float uval = u_in[(size_t)k];            // pre-scatter value (same cell for all dups)
    float nv = (1.0f - GAMMA0) * uval + GAMMA0 * meanexp[win];
    if (win == r) u_out[(size_t)k] = nv;     // the single winning write
    float contrib = sumS[r] / (nv + EPSV);   // gather-after-scatter value

    __shared__ float sh[4];
    int lane = threadIdx.x & 63, wid = threadIdx.x >> 6;
    for (int off = 32; off; off >>= 1) contrib += __shfl_down(contrib, off);
    if (lane == 0) sh[wid] = contrib;
    __syncthreads();
    if (threadIdx.x == 0)
        partial[blockIdx.x] = (sh[0] + sh[1]) + (sh[2] + sh[3]);
}

// ---------------- kernel 4: final loss reduce ----------------
__global__ void k_final(const float* __restrict__ partial, float* __restrict__ out) {
    float v = (threadIdx.x < R_TOT / 256) ? partial[threadIdx.x] : 0.0f;
    __shared__ float sh[4];
    int lane = threadIdx.x & 63, wid = threadIdx.x >> 6;
    for (int off = 32; off; off >>= 1) v += __shfl_down(v, off);
    if (lane == 0) sh[wid] = v;
    __syncthreads();
    if (threadIdx.x == 0)
        out[0] = ((sh[0] + sh[1]) + (sh[2] + sh[3])) * (1.0f / BATCH);
}

extern "C" void kernel_launch(void* const* d_in, const int* in_sizes, int n_in,
                              void* d_out, int out_size, void* d_ws, size_t ws_size,
                              hipStream_t stream) {
    const float* pred    = (const float*)d_in[0];   // (4096, 1010)
    const float* u       = (const float*)d_in[1];   // (10001, 10001)
    const int*   user_id = (const int*)d_in[2];     // (4096,)
    const int*   item_id = (const int*)d_in[3];     // (4096, 10) flat

    float* out   = (float*)d_out;   // [0] = loss, [1..] = u_new
    float* u_out = out + 1;

    char* w = (char*)d_ws;
    int*      hkey    = (int*)w;      w += HSIZE * sizeof(int);
    int*      hval    = (int*)w;      w += HSIZE * sizeof(int);
    unsigned* Minv    = (unsigned*)w; w += 64;
    float*    meanexp = (float*)w;    w += R_TOT * sizeof(float);
    float*    sumS    = (float*)w;    w += R_TOT * sizeof(float);
    int*      keys    = (int*)w;      w += R_TOT * sizeof(int);
    float*    partial = (float*)w;    w += 256 * sizeof(float);

    // one fill: hkey=-1 (empty), hval=-1 (< any r), Minv=0xFFFFFFFF (atomicMin identity)
    hipMemsetAsync(hkey, 0xFF, HSIZE * 2 * sizeof(int) + 64, stream);

    k_rowstat<<<BATCH, 256, 0, stream>>>(pred, Minv);
    k_rowsums<<<BATCH, 256, 0, stream>>>(pred, Minv, user_id, item_id,
                                         meanexp, sumS, keys, hkey, hval);

    // Bulk copy u -> u_new (misaligned-load/aligned-store; the 800 MB HBM floor)
    k_copy<<<2048, 256, 0, stream>>>(u, out);

    k_scatter_loss<<<R_TOT / 256, 256, 0, stream>>>(u, meanexp, sumS, keys, hkey, hval,
                                                    u_out, partial);
    k_final<<<1, 256, 0, stream>>>(partial, out);
}

// Round 5
// 199.347 us; speedup vs baseline: 1.5141x; 1.5141x over previous
//
#include <hip/hip_runtime.h>
#include <cmath>

#define NUM_POS 10
#define NEG 1000
#define COLS 1010          // NUM_POS + NEG
#define BATCH 4096
#define USERS 10001
#define ITEMS 10001
#define R_TOT (BATCH * NUM_POS)   // 40960
#define HSIZE (1 << 17)
#define GAMMA0 0.1f
#define EPSV 1e-10f

#define N_U 100020001LL            // USERS*ITEMS elements in u
// out[0]=loss, out[1..N_U]=u_new.  Quads on out's 16B grid: out4[k]=out[4k..4k+3]
// valid full quads: k = 1 .. 25004999  (covers out[4..100019999])
#define KMAX 25005000LL
#define CPY_THREADS 12502500LL     // ceil((KMAX-1)/2)
#define CPY_BLOCKS  48838          // ceil(CPY_THREADS/256)

// ---- copy kernel: out4[k] = {u4[k-1].w, u4[k].xyz} — branchless, 2 quads/thread ----
__global__ void k_copy(const float* __restrict__ u, float* __restrict__ out) {
    const float4* __restrict__ u4 = (const float4*)u;
    float4* __restrict__ o4 = (float4*)out;
    long long tid = (long long)blockIdx.x * 256 + threadIdx.x;

    long long k = 1 + tid;                    // pass 1: k in [1, CPY_THREADS]
    if (k < KMAX) {
        float4 a = u4[k];                     // aligned 16B load
        float4 b = u4[k - 1];                 // aligned 16B load (overlaps neighbor lane)
        o4[k] = make_float4(b.w, a.x, a.y, a.z);
    }
    k += CPY_THREADS;                         // pass 2
    if (k < KMAX) {
        float4 a = u4[k];
        float4 b = u4[k - 1];
        o4[k] = make_float4(b.w, a.x, a.y, a.z);
    }
    if (blockIdx.x == 0 && threadIdx.x == 0) {
        out[1] = u[0]; out[2] = u[1]; out[3] = u[2];
        out[100020000] = u[100019999];
        out[100020001] = u[100020000];
    }
}

// ---------------- kernel 1: per-row max(neg) - min(pos) ----------------
__global__ void k_rowstat(const float* __restrict__ pred, float* __restrict__ rowM) {
    int b = blockIdx.x;
    const float* row = pred + (size_t)b * COLS;
    float mn = INFINITY, mx = -INFINITY;
    for (int c = threadIdx.x; c < COLS; c += 256) {
        float v = row[c];
        if (c < NUM_POS) mn = fminf(mn, v);
        else             mx = fmaxf(mx, v);
    }
    __shared__ float smn[4], smx[4];
    int lane = threadIdx.x & 63, wid = threadIdx.x >> 6;
    for (int off = 32; off; off >>= 1) {
        mn = fminf(mn, __shfl_down(mn, off));
        mx = fmaxf(mx, __shfl_down(mx, off));
    }
    if (lane == 0) { smn[wid] = mn; smx[wid] = mx; }
    __syncthreads();
    if (threadIdx.x == 0) {
        mn = fminf(fminf(smn[0], smn[1]), fminf(smn[2], smn[3]));
        mx = fmaxf(fmaxf(smx[0], smx[1]), fmaxf(smx[2], smx[3]));
        rowM[b] = mx - mn;   // max over p,j of margin within row b
    }
}

// ---------------- kernel 2: global max over 4096 row maxima ----------------
__global__ void k_gmax(const float* __restrict__ rowM, float* __restrict__ Mout) {
    float mx = -INFINITY;
    for (int i = threadIdx.x; i < BATCH; i += 256) mx = fmaxf(mx, rowM[i]);
    __shared__ float smx[4];
    int lane = threadIdx.x & 63, wid = threadIdx.x >> 6;
    for (int off = 32; off; off >>= 1) mx = fmaxf(mx, __shfl_down(mx, off));
    if (lane == 0) smx[wid] = mx;
    __syncthreads();
    if (threadIdx.x == 0)
        Mout[0] = fmaxf(fmaxf(smx[0], smx[1]), fmaxf(smx[2], smx[3]));
}

// -------- kernel 3: per-row E,F sums; emit meanexp/sumS/keys per (b,p) --------
__global__ void k_rowsums(const float* __restrict__ pred, const float* __restrict__ Mptr,
                          const int* __restrict__ user_id, const int* __restrict__ item_id,
                          float* __restrict__ meanexp, float* __restrict__ sumS,
                          int* __restrict__ keys) {
    int b = blockIdx.x;
    float M = Mptr[0];
    const float* row = pred + (size_t)b * COLS;
    float e = 0.f, f = 0.f;
    for (int c = NUM_POS + threadIdx.x; c < COLS; c += 256) {
        float v = row[c];
        float w = expf(v - M);
        e += w; f += v * w;
    }
    __shared__ float sh[8], bc[2];
    int lane = threadIdx.x & 63, wid = threadIdx.x >> 6;
    for (int off = 32; off; off >>= 1) { e += __shfl_down(e, off); f += __shfl_down(f, off); }
    if (lane == 0) { sh[wid] = e; sh[4 + wid] = f; }
    __syncthreads();
    if (threadIdx.x == 0) {
        bc[0] = (sh[0] + sh[1]) + (sh[2] + sh[3]);
        bc[1] = (sh[4] + sh[5]) + (sh[6] + sh[7]);
    }
    __syncthreads();
    if (threadIdx.x < NUM_POS) {
        float E = bc[0], F = bc[1];
        int p = threadIdx.x;
        int r = b * NUM_POS + p;
        float pos = row[p];
        float s = expf(-pos);
        meanexp[r] = s * E * (1.0f / NEG);
        sumS[r]    = s * (F - pos * E);
        keys[r]    = user_id[b] * ITEMS + item_id[r];
    }
}

// -------- kernel 4: hash-insert keys, winner = max r per key (last write wins) --------
__device__ __forceinline__ unsigned hash_key(int k) {
    return (((unsigned)k * 2654435761u) >> 13) & (HSIZE - 1);
}

__global__ void k_insert(const int* __restrict__ keys, int* __restrict__ hkey,
                         int* __restrict__ hval) {
    int r = blockIdx.x * 256 + threadIdx.x;
    if (r >= R_TOT) return;
    int k = keys[r];
    unsigned s = hash_key(k);
    while (true) {
        int old = atomicCAS(&hkey[s], -1, k);
        if (old == -1 || old == k) { atomicMax(&hval[s], r); break; }
        s = (s + 1) & (HSIZE - 1);
    }
}

// -------- kernel 5: scatter winners into u_out, accumulate loss partials --------
__global__ void k_scatter_loss(const float* __restrict__ u_in,
                               const float* __restrict__ meanexp,
                               const float* __restrict__ sumS,
                               const int* __restrict__ keys,
                               const int* __restrict__ hkey, const int* __restrict__ hval,
                               float* __restrict__ u_out, float* __restrict__ partial) {
    int r = blockIdx.x * 256 + threadIdx.x;
    int k = keys[r];
    unsigned s = hash_key(k);
    while (hkey[s] != k) s = (s + 1) & (HSIZE - 1);
    int win = hval[s];                       // last duplicate index wins
    float uval = u_in[(size_t)k];            // pre-scatter value (same cell for all dups)
    float nv = (1.0f - GAMMA0) * uval + GAMMA0 * meanexp[win];
    if (win == r) u_out[(size_t)k] = nv;     // the single winning write
    float contrib = sumS[r] / (nv + EPSV);   // gather-after-scatter value

    __shared__ float sh[4];
    int lane = threadIdx.x & 63, wid = threadIdx.x >> 6;
    for (int off = 32; off; off >>= 1) contrib += __shfl_down(contrib, off);
    if (lane == 0) sh[wid] = contrib;
    __syncthreads();
    if (threadIdx.x == 0)
        partial[blockIdx.x] = (sh[0] + sh[1]) + (sh[2] + sh[3]);
}

// ---------------- kernel 6: final loss reduce ----------------
__global__ void k_final(const float* __restrict__ partial, float* __restrict__ out) {
    float v = (threadIdx.x < R_TOT / 256) ? partial[threadIdx.x] : 0.0f;
    __shared__ float sh[4];
    int lane = threadIdx.x & 63, wid = threadIdx.x >> 6;
    for (int off = 32; off; off >>= 1) v += __shfl_down(v, off);
    if (lane == 0) sh[wid] = v;
    __syncthreads();
    if (threadIdx.x == 0)
        out[0] = ((sh[0] + sh[1]) + (sh[2] + sh[3])) * (1.0f / BATCH);
}

extern "C" void kernel_launch(void* const* d_in, const int* in_sizes, int n_in,
                              void* d_out, int out_size, void* d_ws, size_t ws_size,
                              hipStream_t stream) {
    const float* pred    = (const float*)d_in[0];   // (4096, 1010)
    const float* u       = (const float*)d_in[1];   // (10001, 10001)
    const int*   user_id = (const int*)d_in[2];     // (4096,)
    const int*   item_id = (const int*)d_in[3];     // (4096, 10) flat

    float* out   = (float*)d_out;   // [0] = loss, [1..] = u_new
    float* u_out = out + 1;

    char* w = (char*)d_ws;
    float* rowM    = (float*)w;  w += BATCH * sizeof(float);
    float* Mptr    = (float*)w;  w += 64;
    float* meanexp = (float*)w;  w += R_TOT * sizeof(float);
    float* sumS    = (float*)w;  w += R_TOT * sizeof(float);
    int*   keys    = (int*)w;    w += R_TOT * sizeof(int);
    int*   hkey    = (int*)w;    w += HSIZE * sizeof(int);
    int*   hval    = (int*)w;    w += HSIZE * sizeof(int);
    float* partial = (float*)w;  w += 256 * sizeof(float);

    hipMemsetAsync(hkey, 0xFF, HSIZE * sizeof(int), stream);   // -1 = empty
    hipMemsetAsync(hval, 0x00, HSIZE * sizeof(int), stream);

    k_rowstat<<<BATCH, 256, 0, stream>>>(pred, rowM);
    k_gmax<<<1, 256, 0, stream>>>(rowM, Mptr);
    k_rowsums<<<BATCH, 256, 0, stream>>>(pred, Mptr, user_id, item_id, meanexp, sumS, keys);
    k_insert<<<R_TOT / 256, 256, 0, stream>>>(keys, hkey, hval);

    // Bulk copy u -> u_new (branchless dual-aligned-load; the 800 MB HBM floor)
    k_copy<<<CPY_BLOCKS, 256, 0, stream>>>(u, out);

    k_scatter_loss<<<R_TOT / 256, 256, 0, stream>>>(u, meanexp, sumS, keys, hkey, hval,
                                                    u_out, partial);
    k_final<<<1, 256, 0, stream>>>(partial, out);
}

// Round 6
// 179.802 us; speedup vs baseline: 1.6787x; 1.1087x over previous
//
#include <hip/hip_runtime.h>
#include <cmath>

#define NUM_POS 10
#define NEG 1000
#define COLS 1010          // NUM_POS + NEG
#define BATCH 4096
#define USERS 10001
#define ITEMS 10001
#define R_TOT (BATCH * NUM_POS)   // 40960
#define HSIZE (1 << 17)
#define GAMMA0 0.1f
#define EPSV 1e-10f

#define N_U 100020001LL            // USERS*ITEMS elements in u
// out[0]=loss, out[1..N_U]=u_new.  Quads on out's 16B grid: out4[k]=out[4k..4k+3]
// valid full quads: k = 1 .. 25004999  (covers out[4..100019999])
#define KMAX 25005000LL
#define CPY_QUADS (KMAX - 1)                    // 25004999
#define CPY_BLOCKS ((CPY_QUADS + 255) / 256)    // 97676

// ---- copy kernel: LDS-realign. Global side = pure aligned 1-load/1-store copy ----
__global__ void k_copy(const float* __restrict__ u, float* __restrict__ out) {
    __shared__ float lds[1028];
    const float4* __restrict__ u4 = (const float4*)u;
    float4* __restrict__ o4 = (float4*)out;
    long long K0 = 1 + (long long)blockIdx.x * 256;
    int t = threadIdx.x;
    long long k = K0 + t;
    int nq = (int)((KMAX - K0 < 256) ? (KMAX - K0) : 256);   // active quads this block

    if (t < nq)
        ((float4*)lds)[t] = u4[k - 1];        // aligned global load, aligned LDS write
    if (t == 0)
        ((float4*)lds)[nq] = u4[K0 + nq - 1]; // one extra quad per block
    __syncthreads();
    if (t < nq) {
        // out4[k] = u[4k-1 .. 4k+2]  ==  lds[4t+3 .. 4t+6]
        float x = lds[4 * t + 3], y = lds[4 * t + 4];
        float z = lds[4 * t + 5], w = lds[4 * t + 6];
        o4[k] = make_float4(x, y, z, w);      // aligned global store
    }
    if (blockIdx.x == 0 && t == 0) {
        out[1] = u[0]; out[2] = u[1]; out[3] = u[2];
        out[100020000] = u[100019999];
        out[100020001] = u[100020000];
    }
}

// ---------------- kernel 1: per-row max(neg) - min(pos) ----------------
__global__ void k_rowstat(const float* __restrict__ pred, float* __restrict__ rowM) {
    int b = blockIdx.x;
    const float* row = pred + (size_t)b * COLS;
    float mn = INFINITY, mx = -INFINITY;
    for (int c = threadIdx.x; c < COLS; c += 256) {
        float v = row[c];
        if (c < NUM_POS) mn = fminf(mn, v);
        else             mx = fmaxf(mx, v);
    }
    __shared__ float smn[4], smx[4];
    int lane = threadIdx.x & 63, wid = threadIdx.x >> 6;
    for (int off = 32; off; off >>= 1) {
        mn = fminf(mn, __shfl_down(mn, off));
        mx = fmaxf(mx, __shfl_down(mx, off));
    }
    if (lane == 0) { smn[wid] = mn; smx[wid] = mx; }
    __syncthreads();
    if (threadIdx.x == 0) {
        mn = fminf(fminf(smn[0], smn[1]), fminf(smn[2], smn[3]));
        mx = fmaxf(fmaxf(smx[0], smx[1]), fmaxf(smx[2], smx[3]));
        rowM[b] = mx - mn;   // max over p,j of margin within row b
    }
}

// ---------------- kernel 2: global max over 4096 row maxima ----------------
__global__ void k_gmax(const float* __restrict__ rowM, float* __restrict__ Mout) {
    float mx = -INFINITY;
    for (int i = threadIdx.x; i < BATCH; i += 256) mx = fmaxf(mx, rowM[i]);
    __shared__ float smx[4];
    int lane = threadIdx.x & 63, wid = threadIdx.x >> 6;
    for (int off = 32; off; off >>= 1) mx = fmaxf(mx, __shfl_down(mx, off));
    if (lane == 0) smx[wid] = mx;
    __syncthreads();
    if (threadIdx.x == 0)
        Mout[0] = fmaxf(fmaxf(smx[0], smx[1]), fmaxf(smx[2], smx[3]));
}

// -------- kernel 3: per-row E,F sums; meanexp/sumS/keys; fused hash insert --------
__device__ __forceinline__ unsigned hash_key(int k) {
    return (((unsigned)k * 2654435761u) >> 13) & (HSIZE - 1);
}

__global__ void k_rowsums(const float* __restrict__ pred, const float* __restrict__ Mptr,
                          const int* __restrict__ user_id, const int* __restrict__ item_id,
                          float* __restrict__ meanexp, float* __restrict__ sumS,
                          int* __restrict__ keys, int* __restrict__ hkey,
                          int* __restrict__ hval) {
    int b = blockIdx.x;
    float M = Mptr[0];
    const float* row = pred + (size_t)b * COLS;
    float e = 0.f, f = 0.f;
    for (int c = NUM_POS + threadIdx.x; c < COLS; c += 256) {
        float v = row[c];
        float w = expf(v - M);
        e += w; f += v * w;
    }
    __shared__ float sh[8], bc[2];
    int lane = threadIdx.x & 63, wid = threadIdx.x >> 6;
    for (int off = 32; off; off >>= 1) { e += __shfl_down(e, off); f += __shfl_down(f, off); }
    if (lane == 0) { sh[wid] = e; sh[4 + wid] = f; }
    __syncthreads();
    if (threadIdx.x == 0) {
        bc[0] = (sh[0] + sh[1]) + (sh[2] + sh[3]);
        bc[1] = (sh[4] + sh[5]) + (sh[6] + sh[7]);
    }
    __syncthreads();
    if (threadIdx.x < NUM_POS) {
        float E = bc[0], F = bc[1];
        int p = threadIdx.x;
        int r = b * NUM_POS + p;
        float pos = row[p];
        float s = expf(-pos);
        meanexp[r] = s * E * (1.0f / NEG);
        sumS[r]    = s * (F - pos * E);
        int key = user_id[b] * ITEMS + item_id[r];
        keys[r] = key;
        // hash insert: winner = max r per key (last write wins)
        unsigned sl = hash_key(key);
        while (true) {
            int old = atomicCAS(&hkey[sl], -1, key);
            if (old == -1 || old == key) { atomicMax(&hval[sl], r); break; }
            sl = (sl + 1) & (HSIZE - 1);
        }
    }
}

// -------- kernel 4: scatter winners into u_out, accumulate loss partials --------
__global__ void k_scatter_loss(const float* __restrict__ u_in,
                               const float* __restrict__ meanexp,
                               const float* __restrict__ sumS,
                               const int* __restrict__ keys,
                               const int* __restrict__ hkey, const int* __restrict__ hval,
                               float* __restrict__ u_out, float* __restrict__ partial) {
    int r = blockIdx.x * 256 + threadIdx.x;
    int k = keys[r];
    unsigned s = hash_key(k);
    while (hkey[s] != k) s = (s + 1) & (HSIZE - 1);
    int win = hval[s];                       // last duplicate index wins
    float uval = u_in[(size_t)k];            // pre-scatter value (same cell for all dups)
    float nv = (1.0f - GAMMA0) * uval + GAMMA0 * meanexp[win];
    if (win == r) u_out[(size_t)k] = nv;     // the single winning write
    float contrib = sumS[r] / (nv + EPSV);   // gather-after-scatter value

    __shared__ float sh[4];
    int lane = threadIdx.x & 63, wid = threadIdx.x >> 6;
    for (int off = 32; off; off >>= 1) contrib += __shfl_down(contrib, off);
    if (lane == 0) sh[wid] = contrib;
    __syncthreads();
    if (threadIdx.x == 0)
        partial[blockIdx.x] = (sh[0] + sh[1]) + (sh[2] + sh[3]);
}

// ---------------- kernel 5: final loss reduce ----------------
__global__ void k_final(const float* __restrict__ partial, float* __restrict__ out) {
    float v = (threadIdx.x < R_TOT / 256) ? partial[threadIdx.x] : 0.0f;
    __shared__ float sh[4];
    int lane = threadIdx.x & 63, wid = threadIdx.x >> 6;
    for (int off = 32; off; off >>= 1) v += __shfl_down(v, off);
    if (lane == 0) sh[wid] = v;
    __syncthreads();
    if (threadIdx.x == 0)
        out[0] = ((sh[0] + sh[1]) + (sh[2] + sh[3])) * (1.0f / BATCH);
}

extern "C" void kernel_launch(void* const* d_in, const int* in_sizes, int n_in,
                              void* d_out, int out_size, void* d_ws, size_t ws_size,
                              hipStream_t stream) {
    const float* pred    = (const float*)d_in[0];   // (4096, 1010)
    const float* u       = (const float*)d_in[1];   // (10001, 10001)
    const int*   user_id = (const int*)d_in[2];     // (4096,)
    const int*   item_id = (const int*)d_in[3];     // (4096, 10) flat

    float* out   = (float*)d_out;   // [0] = loss, [1..] = u_new
    float* u_out = out + 1;

    char* w = (char*)d_ws;
    int*   hkey    = (int*)w;    w += HSIZE * sizeof(int);
    int*   hval    = (int*)w;    w += HSIZE * sizeof(int);
    float* rowM    = (float*)w;  w += BATCH * sizeof(float);
    float* Mptr    = (float*)w;  w += 64;
    float* meanexp = (float*)w;  w += R_TOT * sizeof(float);
    float* sumS    = (float*)w;  w += R_TOT * sizeof(float);
    int*   keys    = (int*)w;    w += R_TOT * sizeof(int);
    float* partial = (float*)w;  w += 256 * sizeof(float);

    // one fill: hkey=-1 (empty), hval=-1 (< any r, atomicMax identity)
    hipMemsetAsync(hkey, 0xFF, HSIZE * 2 * sizeof(int), stream);

    k_rowstat<<<BATCH, 256, 0, stream>>>(pred, rowM);
    k_gmax<<<1, 256, 0, stream>>>(rowM, Mptr);
    k_rowsums<<<BATCH, 256, 0, stream>>>(pred, Mptr, user_id, item_id,
                                         meanexp, sumS, keys, hkey, hval);

    // Bulk copy u -> u_new (LDS-realigned pure copy; the 800 MB HBM floor)
    k_copy<<<CPY_BLOCKS, 256, 0, stream>>>(u, out);

    k_scatter_loss<<<R_TOT / 256, 256, 0, stream>>>(u, meanexp, sumS, keys, hkey, hval,
                                                    u_out, partial);
    k_final<<<1, 256, 0, stream>>>(partial, out);
}